// Round 5
// baseline (586.912 us; speedup 1.0000x reference)
//
#include <hip/hip_runtime.h>
#include <stdint.h>

#define GD 128
#define H1 128
#define H2 128
#define NBASES 32
#define NREL 8
#define K1 (NREL*GD + GD)   // 1152

typedef __attribute__((ext_vector_type(8))) short bf16x8;
typedef __attribute__((ext_vector_type(4))) float f32x4;

static inline size_t align256(size_t x){ return (x + 255) & ~(size_t)255; }

__device__ __forceinline__ float bf2f(uint32_t u16){
  union { uint32_t u; float f; } c; c.u = (u16 & 0xffffu) << 16; return c.f;
}
__device__ __forceinline__ unsigned short f2bf(float f){
  union { float f; uint32_t u; } c; c.f = f;
  uint32_t u = c.u;
  u += 0x7fffu + ((u >> 16) & 1u);   // RTNE (finite inputs)
  return (unsigned short)(u >> 16);
}

__device__ __forceinline__ void async_copy16(void* lds_dst, const void* gsrc){
  __builtin_amdgcn_global_load_lds(
      (const __attribute__((address_space(1))) uint32_t*)gsrc,
      (__attribute__((address_space(3))) uint32_t*)lds_dst, 16, 0, 0);
}

// ---- B1t[o][k] (bf16, [128][1152]): k<1024 -> W_r^T rows, else root^T ----
__global__ void k_build_B1t(const float* __restrict__ comp, const float* __restrict__ basis,
                            const float* __restrict__ root, unsigned short* __restrict__ B1t){
  int idx = blockIdx.x*blockDim.x + threadIdx.x;
  if (idx >= H1*K1) return;
  int nn = idx / K1, kk = idx % K1;
  float v;
  if (kk < NREL*GD){
    int r = kk >> 7, i = kk & 127;
    float acc = 0.f;
    #pragma unroll
    for (int b = 0; b < NBASES; ++b)
      acc += comp[r*NBASES + b] * basis[((size_t)b*GD + i)*H1 + nn];
    v = acc;
  } else {
    v = root[(size_t)(kk - NREL*GD)*H1 + nn];
  }
  B1t[idx] = f2bf(v);
}

// ---- B2t[c][k] (bf16, [512][128]) = [Wk|Wq|Wv|Wskip]^T ; Bb = biases (512 f32) ----
__global__ void k_build_B2t(const float* __restrict__ wk, const float* __restrict__ wq,
                            const float* __restrict__ wv, const float* __restrict__ wsk,
                            const float* __restrict__ bk, const float* __restrict__ bq,
                            const float* __restrict__ bv, const float* __restrict__ bs,
                            unsigned short* __restrict__ B2t, float* __restrict__ Bb){
  int idx = blockIdx.x*blockDim.x + threadIdx.x;
  if (idx < 512*H1){
    int c = idx / H1, k = idx % H1;
    const float* w = (c < 128) ? wk : (c < 256) ? wq : (c < 384) ? wv : wsk;
    B2t[idx] = f2bf(w[(size_t)k*H2 + (c & 127)]);
  }
  if (idx < 512){
    const float* b = (idx < 128) ? bk : (idx < 256) ? bq : (idx < 384) ? bv : bs;
    Bb[idx] = b[idx & 127];
  }
}

__global__ void k_cast_x(const float* __restrict__ x, unsigned short* __restrict__ xbf, int cnt){
  int idx = blockIdx.x*blockDim.x + threadIdx.x;
  if (idx < cnt) xbf[idx] = f2bf(x[idx]);
}

// d-major histogram (for edge2 lists)
__global__ void k_hist_d(const int* __restrict__ dst, int* __restrict__ deg, int E){
  int e = blockIdx.x*blockDim.x + threadIdx.x;
  if (e < E) atomicAdd(&deg[dst[e]], 1);
}
// r-major histogram: bin = typ*n + dst (for fused1 lists)
__global__ void k_hist_rd(const int* __restrict__ dst, const int* __restrict__ typ,
                          int* __restrict__ cnt, int E, int n){
  int e = blockIdx.x*blockDim.x + threadIdx.x;
  if (e < E) atomicAdd(&cnt[typ[e]*n + dst[e]], 1);
}

// ---- parallel scan, stage A: per-block (8192) local exclusive scan + block total ----
__global__ void k_scanA(const int* __restrict__ deg, int* __restrict__ off,
                        int* __restrict__ btot, int len){
  __shared__ int wsum[16];
  int t = threadIdx.x, lane = t & 63, w = t >> 6;
  int i0 = blockIdx.x*8192 + t*8;
  int v[8];
  if (i0 + 7 < len){
    int4 va = *(const int4*)(deg + i0);
    int4 vb = *(const int4*)(deg + i0 + 4);
    v[0]=va.x; v[1]=va.y; v[2]=va.z; v[3]=va.w;
    v[4]=vb.x; v[5]=vb.y; v[6]=vb.z; v[7]=vb.w;
  } else {
    #pragma unroll
    for (int u = 0; u < 8; ++u) v[u] = (i0+u < len) ? deg[i0+u] : 0;
  }
  int s[8]; s[0] = v[0];
  #pragma unroll
  for (int u = 1; u < 8; ++u) s[u] = s[u-1] + v[u];
  int x = s[7];
  #pragma unroll
  for (int d = 1; d < 64; d <<= 1){
    int u = __shfl_up(x, d, 64);
    if (lane >= d) x += u;
  }
  if (lane == 63) wsum[w] = x;
  __syncthreads();
  if (t < 16){
    int y = wsum[t];
    #pragma unroll
    for (int d = 1; d < 16; d <<= 1){
      int u = __shfl_up(y, d, 16);
      if (t >= d) y += u;
    }
    wsum[t] = y;
  }
  __syncthreads();
  int woff = (w > 0) ? wsum[w-1] : 0;
  int excl = woff + x - s[7];
  #pragma unroll
  for (int u = 0; u < 8; ++u)
    if (i0+u < len) off[i0+u] = excl + s[u] - v[u];
  if (t == 0) btot[blockIdx.x] = wsum[15];
}

// ---- scan stage B: add prefix of block totals; emit cursor copy; write sentinel ----
__global__ void k_scanB(const int* __restrict__ btot, int* __restrict__ off,
                        int* __restrict__ cursor, int len, int sentinel){
  int t = threadIdx.x, bid = blockIdx.x;
  int add = 0;
  for (int j = 0; j < bid; ++j) add += btot[j];
  int i0 = bid*8192 + t*8;
  #pragma unroll
  for (int u = 0; u < 8; ++u){
    int i = i0 + u;
    if (i < len){ int val = off[i] + add; off[i] = val; cursor[i] = val; }
  }
  if (bid == 0 && t == 0) off[len] = sentinel;
}

__global__ void k_scatter_d(const int* __restrict__ src, const int* __restrict__ dst,
                            const int* __restrict__ typ, int* __restrict__ cursor,
                            int* __restrict__ pk, int E){
  int e = blockIdx.x*blockDim.x + threadIdx.x;
  if (e >= E) return;
  int pos = atomicAdd(&cursor[dst[e]], 1);
  pk[pos] = src[e] | (typ[e] << 20);
}
__global__ void k_scatter_rd(const int* __restrict__ src, const int* __restrict__ dst,
                             const int* __restrict__ typ, int* __restrict__ cursor,
                             int* __restrict__ pk, int E, int n){
  int e = blockIdx.x*blockDim.x + threadIdx.x;
  if (e >= E) return;
  int pos = atomicAdd(&cursor[typ[e]*n + dst[e]], 1);
  pk[pos] = src[e];
}

// ==== fused RGCN: per 64-node tile, loop r (8 rels + root): build A_r in LDS from
// (r,dst)-sorted edges, MFMA-accumulate A_r @ W_r^T. No Abig materialization. ====
__launch_bounds__(256)
__global__ void k_fused1(const int* __restrict__ off_rd, const int* __restrict__ pk_rd,
                         const unsigned short* __restrict__ xbf,
                         const unsigned short* __restrict__ B1t,
                         const float* __restrict__ bias, unsigned short* __restrict__ h,
                         int n){
  __shared__ char lds[49152];        // A: 64x256B @0 (16KB), B: 128x256B @16384 (32KB)
  const uint32_t* x32 = (const uint32_t*)xbf;
  int t = threadIdx.x, lane = t & 63, wave = t >> 6;
  int node0 = blockIdx.x * 64;
  int mrow = lane & 15, quad = lane >> 4;
  int wrow = (wave & 1) * 32, wcol = (wave >> 1) * 64;
  int fila0 = wave * 16;             // A-fill rows for this wave
  int brow = t >> 4, bphys = t & 15; // B staging decomposition

  f32x4 acc[2][4];
  #pragma unroll
  for (int i = 0; i < 2; ++i)
    #pragma unroll
    for (int j = 0; j < 4; ++j) acc[i][j] = (f32x4){0.f,0.f,0.f,0.f};

  for (int it = 0; it < 9; ++it){
    __syncthreads();
    // ---- stage W_it tile (B1t rows, k-cols [it*128, it*128+128)), XOR-swizzled ----
    {
      const unsigned short* Bbase = B1t + it*128;
      #pragma unroll
      for (int q = 0; q < 8; ++q){
        int nrow = q*16 + brow;
        int logical = bphys ^ (nrow & 15);
        async_copy16(lds + 16384 + q*4096 + wave*1024,
                     Bbase + (size_t)nrow*K1 + logical*8);
      }
    }
    // ---- fill A-tile rows [fila0, fila0+16) ----
    if (it < 8){
      int nb = node0 + fila0;
      int idx = nb + (lane < 16 ? lane : 16);
      if (idx > n) idx = n;
      int ov = off_rd[(size_t)it*n + idx];     // lanes 0..16 hold boundaries
      int o0 = __builtin_amdgcn_readlane(ov, 0);
      int T  = __builtin_amdgcn_readlane(ov, 16) - o0;
      int cur = 0, bstart = 0;
      int bend = __builtin_amdgcn_readlane(ov, 1) - o0;
      float a0 = 0.f, a1 = 0.f;
      for (int jb = 0; jb < T; jb += 64){
        int m = T - jb; if (m > 64) m = 64;
        int pj = (lane < m) ? pk_rd[o0 + jb + lane] : 0;
        int p = __builtin_amdgcn_readlane(pj, 0);
        uint32_t xv = x32[(size_t)p*64 + lane];
        for (int jj = 0; jj < m; ++jj){
          int absj = jb + jj;
          while (cur < 16 && absj == bend){
            int c = bend - bstart;
            float inv = (c > 0) ? 1.f/(float)c : 0.f;
            uint32_t pkd = (uint32_t)f2bf(a0*inv) | ((uint32_t)f2bf(a1*inv) << 16);
            int row = fila0 + cur;
            int phys = (lane >> 2) ^ (row & 15);
            *(uint32_t*)(lds + row*256 + phys*16 + (lane & 3)*4) = pkd;
            a0 = 0.f; a1 = 0.f; bstart = bend; ++cur;
            bend = __builtin_amdgcn_readlane(ov, (cur < 16 ? cur : 15) + 1) - o0;
          }
          uint32_t xc = xv;
          if (jj + 1 < m){
            p = __builtin_amdgcn_readlane(pj, jj + 1);
            xv = x32[(size_t)p*64 + lane];
          }
          a0 += bf2f(xc); a1 += bf2f(xc >> 16);
        }
      }
      while (cur < 16){
        int c = bend - bstart;
        float inv = (c > 0) ? 1.f/(float)c : 0.f;
        uint32_t pkd = (uint32_t)f2bf(a0*inv) | ((uint32_t)f2bf(a1*inv) << 16);
        int row = fila0 + cur;
        int phys = (lane >> 2) ^ (row & 15);
        *(uint32_t*)(lds + row*256 + phys*16 + (lane & 3)*4) = pkd;
        a0 = 0.f; a1 = 0.f; bstart = bend; ++cur;
        if (cur < 16) bend = __builtin_amdgcn_readlane(ov, cur + 1) - o0;
      }
    } else {
      // root pass: A-tile row = x[node]
      #pragma unroll 4
      for (int i = 0; i < 16; ++i){
        int node = node0 + fila0 + i;
        uint32_t xv = (node < n) ? x32[(size_t)node*64 + lane] : 0u;
        int row = fila0 + i;
        int phys = (lane >> 2) ^ (row & 15);
        *(uint32_t*)(lds + row*256 + phys*16 + (lane & 3)*4) = xv;
      }
    }
    __syncthreads();   // drains global_load_lds (vmcnt) + A-tile ds_writes
    // ---- MFMA: acc += A_tile(64x128) @ B_tile(128x128)^T, wave quadrant 32x64 ----
    #pragma unroll
    for (int kt = 0; kt < 4; ++kt){
      int chunk = kt*4 + quad;
      bf16x8 af[2], bfr[4];
      #pragma unroll
      for (int i = 0; i < 2; ++i){
        int m = wrow + i*16 + mrow;
        af[i] = *(const bf16x8*)(lds + m*256 + (chunk ^ (m & 15))*16);
      }
      #pragma unroll
      for (int j = 0; j < 4; ++j){
        int nr = wcol + j*16 + mrow;
        bfr[j] = *(const bf16x8*)(lds + 16384 + nr*256 + (chunk ^ (nr & 15))*16);
      }
      #pragma unroll
      for (int i = 0; i < 2; ++i)
        #pragma unroll
        for (int j = 0; j < 4; ++j)
          acc[i][j] = __builtin_amdgcn_mfma_f32_16x16x32_bf16(af[i], bfr[j], acc[i][j], 0, 0, 0);
    }
  }
  // ---- epilogue: h = acc + bias1 (bf16) ----
  #pragma unroll
  for (int j = 0; j < 4; ++j){
    int col = wcol + j*16 + mrow;
    float bcol = bias[col];
    #pragma unroll
    for (int i = 0; i < 2; ++i)
      #pragma unroll
      for (int rg = 0; rg < 4; ++rg){
        int row = wrow + i*16 + quad*4 + rg;
        h[(size_t)(node0 + row)*H1 + col] = f2bf(acc[i][j][rg] + bcol);
      }
  }
}

// ---- GEMM2 (m97-style): [npad,512] = h @ B2t^T + Bb ----
__launch_bounds__(256)
__global__ void k_gemm2(const unsigned short* __restrict__ A, const unsigned short* __restrict__ Bt,
                        const float* __restrict__ Bb, unsigned short* __restrict__ kqv,
                        float* __restrict__ out, int n){
  __shared__ char lds[16384];
  int t = threadIdx.x, lane = t & 63, wave = t >> 6;
  int row0 = blockIdx.x * 128;
  int c0 = blockIdx.y * 128;
  int mrow = lane & 15, quad = lane >> 4;
  int wrow = (wave & 1) * 64, wcol = (wave >> 1) * 64;
  int s = (mrow >> 1) & 3;

  const unsigned short* Asrc = A + (size_t)(row0 + (t >> 2))*H1 + (((t & 3) ^ ((t >> 3) & 3)) << 3);
  const unsigned short* Bsrc = Bt + (size_t)(c0 + (t >> 2))*H1 + (((t & 3) ^ ((t >> 3) & 3)) << 3);
  char* ldsw = lds + wave*1024;

  int aoff = (wrow + mrow)*64 + ((quad ^ s) << 4);
  int boff = 8192 + (wcol + mrow)*64 + ((quad ^ s) << 4);

  f32x4 acc[4][4];
  #pragma unroll
  for (int i = 0; i < 4; ++i)
    #pragma unroll
    for (int j = 0; j < 4; ++j) acc[i][j] = (f32x4){0.f,0.f,0.f,0.f};

  #pragma unroll
  for (int kt = 0; kt < H1; kt += 32){
    __syncthreads();
    async_copy16(ldsw,         Asrc + kt);
    async_copy16(ldsw + 4096,  Asrc + (size_t)64*H1 + kt);
    async_copy16(ldsw + 8192,  Bsrc + kt);
    async_copy16(ldsw + 12288, Bsrc + (size_t)64*H1 + kt);
    __syncthreads();
    bf16x8 af[4], bf[4];
    #pragma unroll
    for (int i = 0; i < 4; ++i) af[i] = *(const bf16x8*)(lds + aoff + i*1024);
    #pragma unroll
    for (int j = 0; j < 4; ++j) bf[j] = *(const bf16x8*)(lds + boff + j*1024);
    #pragma unroll
    for (int i = 0; i < 4; ++i)
      #pragma unroll
      for (int j = 0; j < 4; ++j)
        acc[i][j] = __builtin_amdgcn_mfma_f32_16x16x32_bf16(af[i], bf[j], acc[i][j], 0, 0, 0);
  }
  #pragma unroll
  for (int j = 0; j < 4; ++j){
    int col = c0 + wcol + j*16 + mrow;
    float bcol = Bb[col];
    #pragma unroll
    for (int i = 0; i < 4; ++i)
      #pragma unroll
      for (int rg = 0; rg < 4; ++rg){
        int rr = row0 + wrow + i*16 + quad*4 + rg;
        if (rr >= n) continue;
        float v = acc[i][j][rg] + bcol;
        if (col < 128){
          kqv[(size_t)rr*384 + col] = f2bf(v);
        } else if (col < 256){
          int jj = col - 128;
          kqv[(size_t)rr*384 + 128 + ((jj >> 1) << 2) + (jj & 1)] = f2bf(v);
        } else if (col < 384){
          int jj = col - 256;
          kqv[(size_t)rr*384 + 128 + ((jj >> 1) << 2) + 2 + (jj & 1)] = f2bf(v);
        } else {
          out[(size_t)rr*H2 + (col - 384)] = v;
        }
      }
  }
}

// ---- one wave per dst node: out[d] += sum_e sigmoid(k[d]+q[s])*v[s] ----
__global__ void k_edge2(const int* __restrict__ off, const int* __restrict__ deg,
                        const int* __restrict__ pk, const unsigned short* __restrict__ kqv,
                        float* __restrict__ out, int n){
  int wid = blockIdx.x*(blockDim.x >> 6) + (threadIdx.x >> 6);
  int lane = threadIdx.x & 63;
  if (wid >= n) return;
  const uint32_t* kv32 = (const uint32_t*)kqv;
  uint32_t ku = kv32[(size_t)wid*192 + lane];
  float k0 = bf2f(ku), k1 = bf2f(ku >> 16);
  float a0 = 0.f, a1 = 0.f;
  int o = off[wid], dg = deg[wid];
  for (int jb = 0; jb < dg; jb += 64){
    int pj = (jb + lane < dg) ? pk[o + jb + lane] : 0;
    int m = dg - jb; if (m > 64) m = 64;
    int p = __builtin_amdgcn_readlane(pj, 0);
    uint2 qv = *(const uint2*)(kv32 + (size_t)(p & 0xFFFFF)*192 + 64 + lane*2);
    for (int jj = 0; jj < m; ++jj){
      uint2 qc = qv;
      if (jj + 1 < m){
        p = __builtin_amdgcn_readlane(pj, jj + 1);
        qv = *(const uint2*)(kv32 + (size_t)(p & 0xFFFFF)*192 + 64 + lane*2);
      }
      float q0 = bf2f(qc.x), q1 = bf2f(qc.x >> 16);
      float v0 = bf2f(qc.y), v1 = bf2f(qc.y >> 16);
      float g0 = 1.f / (1.f + __expf(-(k0 + q0)));
      float g1 = 1.f / (1.f + __expf(-(k1 + q1)));
      a0 += g0*v0; a1 += g1*v1;
    }
  }
  float2* op = (float2*)(out + (size_t)wid*H2);
  float2 cur = op[lane];
  cur.x += a0; cur.y += a1;
  op[lane] = cur;
}

extern "C" void kernel_launch(void* const* d_in, const int* in_sizes, int n_in,
                              void* d_out, int out_size, void* d_ws, size_t ws_size,
                              hipStream_t stream){
  const float* x     = (const float*)d_in[0];
  const int*   eidx  = (const int*)  d_in[1];
  const int*   etype = (const int*)  d_in[3];
  const float* basis = (const float*)d_in[4];
  const float* comp  = (const float*)d_in[5];
  const float* root  = (const float*)d_in[6];
  const float* bias1 = (const float*)d_in[7];
  const float* wk    = (const float*)d_in[8];
  const float* bk    = (const float*)d_in[9];
  const float* wq    = (const float*)d_in[10];
  const float* bq    = (const float*)d_in[11];
  const float* wv    = (const float*)d_in[12];
  const float* bv    = (const float*)d_in[13];
  const float* wsk   = (const float*)d_in[14];
  const float* bs    = (const float*)d_in[15];
  const int n = in_sizes[0] / GD;          // 50000
  const int E = in_sizes[3];               // 600000
  const int npad = (n + 127) & ~127;       // 50048
  const int* esrc = eidx;
  const int* edst = eidx + E;
  float* out = (float*)d_out;

  char* w = (char*)d_ws;
  size_t off = 0;
  unsigned short* xbf  = (unsigned short*)(w + off); off = align256(off + (size_t)n*GD*2);
  unsigned short* B1t  = (unsigned short*)(w + off); off = align256(off + (size_t)H1*K1*2);
  unsigned short* B2t  = (unsigned short*)(w + off); off = align256(off + (size_t)512*H1*2);
  float* Bb            = (float*)(w + off);          off = align256(off + 512*4);
  unsigned short* hbuf = (unsigned short*)(w + off); off = align256(off + (size_t)npad*H1*2);
  unsigned short* kqv  = (unsigned short*)(w + off); off = align256(off + (size_t)n*384*2);
  int* deg             = (int*)(w + off);            off = align256(off + (size_t)(n+1)*4);
  int* off_d           = (int*)(w + off);            off = align256(off + (size_t)(n+1)*4);
  int* cur_d           = (int*)(w + off);            off = align256(off + (size_t)n*4);
  int* cnt_rd          = (int*)(w + off);            off = align256(off + (size_t)(8*n+1)*4);
  int* off_rd          = (int*)(w + off);            off = align256(off + (size_t)(8*n+1)*4);
  int* cur_rd          = (int*)(w + off);            off = align256(off + (size_t)8*n*4);
  int* btot_d          = (int*)(w + off);            off = align256(off + 64*4);
  int* btot_rd         = (int*)(w + off);            off = align256(off + 64*4);
  int* pk_d            = (int*)(w + off);            off = align256(off + (size_t)E*4);
  int* pk_rd           = (int*)(w + off);            off = align256(off + (size_t)E*4);

  const int nblk_d  = (n + 8191) / 8192;       // 7
  const int nblk_rd = (8*n + 8191) / 8192;     // 49

  hipMemsetAsync(deg, 0, (size_t)n*4, stream);
  hipMemsetAsync(cnt_rd, 0, (size_t)8*n*4, stream);

  k_build_B1t<<<(H1*K1 + 255)/256, 256, 0, stream>>>(comp, basis, root, B1t);
  k_build_B2t<<<(512*H1 + 255)/256, 256, 0, stream>>>(wk, wq, wv, wsk, bk, bq, bv, bs, B2t, Bb);
  k_cast_x<<<(n*GD + 255)/256, 256, 0, stream>>>(x, xbf, n*GD);
  k_hist_d<<<(E + 255)/256, 256, 0, stream>>>(edst, deg, E);
  k_hist_rd<<<(E + 255)/256, 256, 0, stream>>>(edst, etype, cnt_rd, E, n);
  k_scanA<<<nblk_d, 1024, 0, stream>>>(deg, off_d, btot_d, n);
  k_scanB<<<nblk_d, 1024, 0, stream>>>(btot_d, off_d, cur_d, n, E);
  k_scanA<<<nblk_rd, 1024, 0, stream>>>(cnt_rd, off_rd, btot_rd, 8*n);
  k_scanB<<<nblk_rd, 1024, 0, stream>>>(btot_rd, off_rd, cur_rd, 8*n, E);
  k_scatter_d<<<(E + 255)/256, 256, 0, stream>>>(esrc, edst, etype, cur_d, pk_d, E);
  k_scatter_rd<<<(E + 255)/256, 256, 0, stream>>>(esrc, edst, etype, cur_rd, pk_rd, E, n);
  k_fused1<<<npad/64, 256, 0, stream>>>(off_rd, pk_rd, xbf, B1t, bias1, hbuf, n);
  k_gemm2<<<dim3(npad/128, 4), 256, 0, stream>>>(hbuf, B2t, Bb, kqv, out, n);
  k_edge2<<<(n + 3)/4, 256, 0, stream>>>(off_d, deg, pk_d, kqv, out, n);
}